// Round 1
// 465.178 us; speedup vs baseline: 1.0073x; 1.0073x over previous
//
#include <hip/hip_runtime.h>
#include <float.h>
#include <math.h>

#define HH 224
#define WW 224
#define PLANE (HH*WW)
#define FRAME (3*HH*WW)   // 150528
#define LFR 64            // frames per batch
#define NP 63             // pairs per batch
#define NB 8              // batch
#define NM 16             // MAX_NUM_FRAME
#define EPSV 1e-6f

#define RSLAB 32            // output rows per slab
#define NSLAB (HH / RSLAB)  // 7
#define DROWS (RSLAB + 6)   // 38 D-rows incl. halo
#define LDW 232             // padded LDS row: 4 zero | 224 data | 4 zero (16B-aligned quads)
#define NQ 56               // float4 quads per row (224/4)
#define UNITS (DROWS * NQ)  // 2128 load units per block
#define BLK 512

// ---------------- Stage 1: per-pair-slab diff score ----------------
// D(r,c) = sum_ch (x[b,l]-x[b,l+1])   (zero outside image; zero-padded cols in LDS)
// H(r,c) = sum_{dc=-3..3} D(r,c+dc)   (cooperative float4 pass, LDS->LDS)
// out(i,c) = | w * sum_{dr=-3..3} H(i+dr,c) + eps |
__global__ __launch_bounds__(BLK) void diff_kernel(
    const float* __restrict__ x, const float* __restrict__ cw,
    float* __restrict__ dsp)
{
    const int slab = blockIdx.x;         // 0..6
    const int pair = blockIdx.y;         // 0..503
    const int b = pair / NP;
    const int l = pair - b * NP;
    const float* f0 = x + (size_t)(b * LFR + l) * FRAME;
    const float* f1 = f0 + FRAME;
    const float w = cw[0];

    const int rBase = slab * RSLAB - 3;  // global row of local D-row 0

    __shared__ float Dl[DROWS][LDW];     // 35.3 KB
    __shared__ float Hl[DROWS][WW];      // 34.0 KB
    __shared__ float red[8];

    const int tid = threadIdx.x;

    // Zero the 4-col pads on both sides (38 rows x 2 sides, float4 each).
    if (tid < 2 * DROWS) {
        const int r = tid >> 1;
        const int col = (tid & 1) ? (LDW - 4) : 0;
        *(float4*)&Dl[r][col] = make_float4(0.f, 0.f, 0.f, 0.f);
    }

    // Phase A: flat cooperative float4 load loop, no per-row branches on loads.
    for (int u = tid; u < UNITS; u += BLK) {
        const int r  = u / NQ;           // local D-row
        const int cq = u - r * NQ;       // column quad
        const int gr = rBase + r;        // global row
        float4 v = make_float4(0.f, 0.f, 0.f, 0.f);
        if (gr >= 0 && gr < HH) {
            const int off = (gr * WW + cq * 4) >> 2;   // float4 index
            const float4* p0 = (const float4*)f0;
            const float4* p1 = (const float4*)f1;
            const float4 a0 = p0[off];
            const float4 a1 = p0[off + PLANE/4];
            const float4 a2 = p0[off + 2*PLANE/4];
            const float4 b0 = p1[off];
            const float4 b1 = p1[off + PLANE/4];
            const float4 b2 = p1[off + 2*PLANE/4];
            v.x = (a0.x - b0.x) + (a1.x - b1.x) + (a2.x - b2.x);
            v.y = (a0.y - b0.y) + (a1.y - b1.y) + (a2.y - b2.y);
            v.z = (a0.z - b0.z) + (a1.z - b1.z) + (a2.z - b2.z);
            v.w = (a0.w - b0.w) + (a1.w - b1.w) + (a2.w - b2.w);
        }
        *(float4*)&Dl[r][4 + cq * 4] = v;
    }
    __syncthreads();

    // Phase A2: cooperative horizontal 7-sum, float4 in / float4 out.
    // Quad (r,cq) covers output cols 4cq..4cq+3; needs padded cols 4cq..4cq+11.
    // Add order per output kept identical to the verified scalar version
    // (ascending columns, sequential chain) so scores are bit-identical.
    for (int u = tid; u < UNITS; u += BLK) {
        const int r  = u / NQ;
        const int cq = u - r * NQ;
        const float* row = &Dl[r][4 + cq * 4];
        const float4 dm = *(const float4*)(row - 4);  // padded cols 4cq-4..4cq-1
        const float4 dc = *(const float4*)(row);      // 4cq..4cq+3
        const float4 dp = *(const float4*)(row + 4);  // 4cq+4..4cq+7
        const float h0 = ((((((dm.y + dm.z) + dm.w) + dc.x) + dc.y) + dc.z) + dc.w);
        const float h1 = ((((((dm.z + dm.w) + dc.x) + dc.y) + dc.z) + dc.w) + dp.x);
        const float h2 = ((((((dm.w + dc.x) + dc.y) + dc.z) + dc.w) + dp.x) + dp.y);
        const float h3 = ((((((dc.x + dc.y) + dc.z) + dc.w) + dp.x) + dp.y) + dp.z);
        *(float4*)&Hl[r][cq * 4] = make_float4(h0, h1, h2, h3);
    }
    __syncthreads();

    // Phase B: per-column vertical 7-sum over Hl — 38 scalar LDS reads/lane.
    float acc = 0.f;
    if (tid < WW) {
        const int c = tid;
        float ring[8];
        #pragma unroll
        for (int r = 0; r < DROWS; ++r) {
            ring[r & 7] = Hl[r][c];
            if (r >= 6) {
                float v = 0.f;
                #pragma unroll
                for (int k = 0; k < 7; ++k) v += ring[(r - 6 + k) & 7];
                acc += fabsf(w * v + EPSV);
            }
        }
    }

    // Block reduction (inactive threads hold 0)
    #pragma unroll
    for (int off = 32; off >= 1; off >>= 1)
        acc += __shfl_down(acc, off, 64);
    const int wave = tid >> 6;
    if ((tid & 63) == 0) red[wave] = acc;
    __syncthreads();
    if (tid == 0) {
        float s = 0.f;
        #pragma unroll
        for (int k = 0; k < 8; ++k) s += red[k];
        dsp[pair * NSLAB + slab] = s;
    }
}

// ---------------- Stage 2: dsp -> cumsum -> argmin indices ----------------
__global__ __launch_bounds__(64) void select_kernel(
    const float* __restrict__ dsp, int* __restrict__ idx)
{
    const int b = blockIdx.x;
    const int lane = threadIdx.x;
    float v = 0.f;
    if (lane < NP) {
        float s = 0.f;
        #pragma unroll
        for (int k = 0; k < NSLAB; ++k) s += dsp[(b * NP + lane) * NSLAB + k];
        v = sqrtf(s);                    // power(diff_score, 0.5)
    }

    float tot = v;
    #pragma unroll
    for (int off = 1; off < 64; off <<= 1)
        tot += __shfl_xor(tot, off, 64);

    float scan = v;
    #pragma unroll
    for (int off = 1; off < 64; off <<= 1) {
        float t = __shfl_up(scan, off, 64);
        if (lane >= off) scan += t;
    }
    const float cum = scan / tot;

    const float interval = 1.0f / (NM - 1);
    for (int m = 0; m < NM; ++m) {
        const float target = (float)m * interval;
        float bv = (lane < NP) ? fabsf(cum - target) : FLT_MAX;
        int bi = lane;
        #pragma unroll
        for (int off = 1; off < 64; off <<= 1) {
            float ov = __shfl_xor(bv, off, 64);
            int oi = __shfl_xor(bi, off, 64);
            if (ov < bv || (ov == bv && oi < bi)) { bv = ov; bi = oi; }
        }
        if (lane == 0) idx[b * NM + m] = bi;
    }
}

// ---------------- Stage 3: gather selected frames ----------------
// 7 float4 per thread; FRAME/4 = 37632 = 21 * 256 * 7.
__global__ __launch_bounds__(256) void gather_kernel(
    const float* __restrict__ x, const int* __restrict__ idx,
    float* __restrict__ out)
{
    const int f = blockIdx.y;            // b*NM + m, 0..127
    const int b = f >> 4;
    const int id = idx[f];
    const float4* src = (const float4*)(x + (size_t)(b * LFR + id) * FRAME);
    float4* dst = (float4*)(out + (size_t)f * FRAME);
    const int i = blockIdx.x * 256 + threadIdx.x;
    #pragma unroll
    for (int k = 0; k < 7; ++k)
        dst[i + k * (21 * 256)] = src[i + k * (21 * 256)];
}

extern "C" void kernel_launch(void* const* d_in, const int* in_sizes, int n_in,
                              void* d_out, int out_size, void* d_ws, size_t ws_size,
                              hipStream_t stream) {
    const float* x  = (const float*)d_in[0];
    const float* cw = (const float*)d_in[1];
    // conv_b is identically zero and cancels in the pair difference.
    float* dsp = (float*)d_ws;                       // 504*7 floats
    int*   idx = (int*)((char*)d_ws + 16384);        // 128 ints

    hipLaunchKernelGGL(diff_kernel, dim3(NSLAB, NB * NP), dim3(BLK), 0, stream,
                       x, cw, dsp);
    hipLaunchKernelGGL(select_kernel, dim3(NB), dim3(64), 0, stream, dsp, idx);
    hipLaunchKernelGGL(gather_kernel, dim3(21, NB * NM), dim3(256), 0, stream,
                       x, idx, (float*)d_out);
}